// Round 4
// baseline (793.806 us; speedup 1.0000x reference)
//
#include <hip/hip_runtime.h>
#include <hip/hip_cooperative_groups.h>

namespace cg = cooperative_groups;

#define DEV __device__ __forceinline__

// ---- quantizer helpers (exact, round-half-even matches jnp.round) ----
DEV float qwt(float w) {
    float y = fminf(fmaxf(w, -1.0f), 0.875f);
    return rintf(y * 8.0f) * 0.125f;
}
DEV int qw8i(float w) {                       // weight -> int in [-8,7]
    float y = fminf(fmaxf(w, -1.0f), 0.875f);
    return (int)rintf(y * 8.0f);
}
DEV int q8i(float x, float a, float b) {      // act -> int in [-8,7]
    float y = fmaf(x, a, b);
    y = fminf(fmaxf(y, -1.0f), 0.875f);
    return (int)rintf(y * 8.0f);
}
DEV float qact(float x, float a, float b) {
    float y = fmaf(x, a, b);
    y = fminf(fmaxf(y, -1.0f), 0.875f);
    return rintf(y * 8.0f) * 0.125f;
}

DEV int dot4(int a, int b, int c) {
#if __has_builtin(__builtin_amdgcn_sdot4)
    return __builtin_amdgcn_sdot4(a, b, c, false);
#else
    c += (int)(signed char)(a)       * (int)(signed char)(b);
    c += (int)(signed char)(a >> 8)  * (int)(signed char)(b >> 8);
    c += (int)(signed char)(a >> 16) * (int)(signed char)(b >> 16);
    c += (int)(signed char)(a >> 24) * (int)(signed char)(b >> 24);
    return c;
#endif
}
DEV unsigned alignpair(unsigned hi, unsigned lo, int bits) {
#if __has_builtin(__builtin_amdgcn_alignbit)
    return __builtin_amdgcn_alignbit(hi, lo, bits);
#else
    return bits ? ((lo >> bits) | (hi << (32 - bits))) : lo;
#endif
}

struct Params {
    const float* x;
    const float* w1; const float* w2; const float* w3; const float* w4; const float* w5;
    const float* fw1; const float* fw2;
    const float* g[7]; const float* bb[7];
    short* y1; short* y2; short* y3; short* y4; short* y5;
    float* z1; float* z2;
    float* part[7];
    float* out;
    int G;
};

// ---------------------------------------------------------------------------
// BN bridge: every block deterministically reduces G x 2C fp32 partials in
// fp64 (fixed tree, identical bits in all blocks), writes folded scale/shift
// into LDS. fold = 1/64 for int16-stored inputs, 1 for float paths.
// ---------------------------------------------------------------------------
template<int C>
DEV void bridge(const float* part, int G, double N,
                const float* gamma, const float* beta,
                float* tsA, float* tbA, float fold, double* dsc)
{
    const int tid = threadIdx.x;
    if (tid < 2 * C * 4) {
        int slot = tid >> 2, ch = tid & 3;
        double s = 0.0;
        for (int g = ch; g < G; g += 4)
            s += (double)part[(size_t)g * 2 * C + slot];
        dsc[tid] = s;
    }
    __syncthreads();
    if (tid < C) {
        double S = dsc[8 * tid]     + dsc[8 * tid + 1] + dsc[8 * tid + 2] + dsc[8 * tid + 3];
        double Q = dsc[8 * tid + 4] + dsc[8 * tid + 5] + dsc[8 * tid + 6] + dsc[8 * tid + 7];
        double mean = S / N;
        double var  = Q / N - mean * mean;
        double inv  = 1.0 / sqrt(var + 1e-5);
        double sc   = (double)gamma[tid] * inv;
        tsA[tid] = (float)sc * fold;
        tbA[tid] = (float)((double)beta[tid] - mean * sc);
    }
    __syncthreads();
}

// ---------------------------------------------------------------------------
// One conv layer (stride 2, VALID), int8/dot4, operating on 16-row tiles
// aligned to the block's row ownership. Same numerics as the verified
// standalone conv_k (round 3, absmax 0.0).
// ---------------------------------------------------------------------------
template<int CIN,int COUT,int K,int LINP,int LOUT,int LOUTP,int P,bool IN_FLOAT,int LIN>
DEV void conv_layer(const void* in_, const float* w, short* out, float* partial,
                    int G, signed char* uni, int* wql,
                    const float* tsA, const float* tbA, float (*redf)[40])
{
    constexpr int KW   = (K + 3) / 4;
    constexpr int NE   = P + 2 * KW - 1;
    constexpr int ND   = (2 * (NE - 1) + 3) / 4 + 2;
    constexpr int LO_P = (LOUT + P - 1) / P;
    constexpr int GROUPS = 16 * LO_P;

    const int tid = threadIdx.x;
    const int bid = blockIdx.x;

    // pack quantized weights into LDS dwords (byte u of dword j = tap 4j+u)
    for (int i = tid; i < COUT * CIN * KW; i += 256) {
        int j = i % KW, cc = i / KW;
        unsigned rr = 0;
        for (int u = 0; u < 4; u++) {
            int k = 4 * j + u;
            int bv = (k < K) ? (qw8i(w[cc * K + k]) & 0xff) : 0;
            rr |= (unsigned)bv << (8 * u);
        }
        wql[i] = (int)rr;
    }

    float tsum[COUT], tsq[COUT];
#pragma unroll
    for (int c = 0; c < COUT; c++) { tsum[c] = 0.f; tsq[c] = 0.f; }

    for (int tile = bid; tile < 512; tile += G) {
        const int r0 = tile * 16;
        __syncthreads();   // uni free, wql/tsA ready

        // ---- stage 16 rows: global -> quantized int8 LDS ----
        if constexpr (IN_FLOAT) {
            constexpr int CH = LIN / 2;
            const float2* gp = (const float2*)in_;
            for (int c = tid; c < 16 * CH; c += 256) {
                int r = c / CH, rem = c - r * CH;
                float2 v = gp[(size_t)(r0 + r) * CH + rem];
                int b0 = q8i(v.x, 1.f, 0.f) & 0xff;
                int b1 = q8i(v.y, 1.f, 0.f) & 0xff;
                *(unsigned short*)(uni + r * LINP + rem * 2) =
                    (unsigned short)(b0 | (b1 << 8));
            }
        } else {
            constexpr int CH  = CIN * LINP / 8;
            constexpr int CHC = LINP / 8;
            const int4* gp = (const int4*)((const short*)in_ + (size_t)r0 * CIN * LINP);
            for (int c = tid; c < 16 * CH; c += 256) {
                int rem = c % CH;
                int ci = rem / CHC;
                float a = tsA[ci], bo = tbA[ci];
                int4 v = gp[c];
                int vs[4] = { v.x, v.y, v.z, v.w };
                unsigned pk[2];
#pragma unroll
                for (int u = 0; u < 2; u++) {
                    unsigned pp = 0;
#pragma unroll
                    for (int j = 0; j < 2; j++) {
                        int word = vs[u * 2 + j];
                        int b0 = q8i((float)(short)(word & 0xffff), a, bo) & 0xff;
                        int b1 = q8i((float)(short)(word >> 16),    a, bo) & 0xff;
                        pp |= (unsigned)(b0 | (b1 << 8)) << (16 * j);
                    }
                    pk[u] = pp;
                }
                ((uint2*)uni)[c] = make_uint2(pk[0], pk[1]);
            }
        }
        __syncthreads();

        // ---- compute ----
#pragma unroll 1
        for (int g = tid; g < GROUPS; g += 256) {
            int r = g / LO_P;
            int l0   = (g - r * LO_P) * P;
            int pact = min(P, LOUT - l0);

            int acc[COUT][P];
#pragma unroll
            for (int co = 0; co < COUT; co++)
#pragma unroll
                for (int p = 0; p < P; p++) acc[co][p] = 0;

            const int ibase = r * CIN * LINP + 2 * l0;
            const int sh    = (P % 2 == 0) ? 0 : (ibase & 3);

            for (int ci = 0; ci < CIN; ci++) {
                const int* sp = (const int*)uni + ((ci * LINP + (ibase & ~3)) >> 2);
                int d[ND];
#pragma unroll
                for (int j = 0; j < ND; j++) d[j] = sp[j];
                int e[NE];
#pragma unroll
                for (int i = 0; i < NE; i++) {
                    int off = sh + 2 * i;
                    e[i] = (int)alignpair((unsigned)d[off / 4 + 1], (unsigned)d[off / 4], (off & 3) * 8);
                }
#pragma unroll
                for (int co = 0; co < COUT; co++) {
#pragma unroll
                    for (int j = 0; j < KW; j++) {
                        int wv = wql[(co * CIN + ci) * KW + j];
#pragma unroll
                        for (int p = 0; p < P; p++)
                            acc[co][p] = dot4(e[p + 2 * j], wv, acc[co][p]);
                    }
                }
            }

            const size_t ob = (size_t)(r0 + r) * COUT * LOUTP + l0;
#pragma unroll
            for (int co = 0; co < COUT; co++) {
                if (pact == P) {
                    short tmp[P];
#pragma unroll
                    for (int p = 0; p < P; p++) {
                        tmp[p] = (short)acc[co][p];
                        float v = (float)acc[co][p] * 0.015625f;
                        tsum[co] += v;
                        tsq[co]   = fmaf(v, v, tsq[co]);
                    }
                    short* op = &out[ob + (size_t)co * LOUTP];
                    if constexpr (P == 1) {
                        op[0] = tmp[0];
                    } else if constexpr (P == 2) {
                        *(short2*)op = make_short2(tmp[0], tmp[1]);
                    } else if constexpr (P == 4) {
                        *(short4*)op = make_short4(tmp[0], tmp[1], tmp[2], tmp[3]);
                    } else if constexpr (P == 8) {
                        *(short4*)op       = make_short4(tmp[0], tmp[1], tmp[2], tmp[3]);
                        *(short4*)(op + 4) = make_short4(tmp[4], tmp[5], tmp[6], tmp[7]);
                    }
                } else {
#pragma unroll
                    for (int p = 0; p < P; p++) {
                        if (p < pact) {
                            out[ob + (size_t)co * LOUTP + p] = (short)acc[co][p];
                            float v = (float)acc[co][p] * 0.015625f;
                            tsum[co] += v;
                            tsq[co]   = fmaf(v, v, tsq[co]);
                        }
                    }
                }
            }
        }
    }

    const int lane = tid & 63, wid = tid >> 6;
#pragma unroll
    for (int co = 0; co < COUT; co++) {
        float s = tsum[co], q = tsq[co];
        for (int off = 32; off > 0; off >>= 1) {
            s += __shfl_down(s, off, 64);
            q += __shfl_down(q, off, 64);
        }
        if (lane == 0) { redf[wid][2 * co] = s; redf[wid][2 * co + 1] = q; }
    }
    __syncthreads();
    if (tid < 2 * COUT)
        partial[(size_t)bid * (2 * COUT) + tid] =
            redf[0][tid] + redf[1][tid] + redf[2][tid] + redf[3][tid];
    __syncthreads();
}

// ---------------------------------------------------------------------------
// FC1: (B,740) x (10,740)^T, one wave per row (same numerics as round 3).
// ---------------------------------------------------------------------------
DEV void fc1_layer(const short* y5, const float* fw1, float* z1, float* partial,
                   int G, float* wqf, const float* tsA, const float* tbA,
                   float (*redf)[40])
{
    const int tid = threadIdx.x;
    const int lane = tid & 63, wid = tid >> 6;

    for (int i = tid; i < 7400; i += 256) wqf[i] = qwt(fw1[i]);
    __syncthreads();

    float tsum[10], tsq[10];
#pragma unroll
    for (int j = 0; j < 10; j++) { tsum[j] = 0.f; tsq[j] = 0.f; }

#pragma unroll 1
    for (int tile = blockIdx.x; tile < 512; tile += G) {
#pragma unroll 1
        for (int pass = 0; pass < 4; pass++) {
            int r = tile * 16 + pass * 4 + wid;
            const short* xr = y5 + (size_t)r * 800;   // 20ch x 40 padded
            float acc[10];
#pragma unroll
            for (int j = 0; j < 10; j++) acc[j] = 0.f;
#pragma unroll 1
            for (int f = lane; f < 740; f += 64) {
                int c = f / 37, pos = f - c * 37;
                float xv = qact((float)xr[c * 40 + pos] * 0.015625f, tsA[c], tbA[c]);
#pragma unroll
                for (int j = 0; j < 10; j++) acc[j] = fmaf(xv, wqf[j * 740 + f], acc[j]);
            }
#pragma unroll
            for (int j = 0; j < 10; j++) {
                float v = acc[j];
                for (int off = 1; off < 64; off <<= 1) v += __shfl_xor(v, off, 64);
                tsum[j] += v; tsq[j] = fmaf(v, v, tsq[j]);
                if (lane == j) z1[(size_t)r * 10 + j] = v;
            }
        }
    }
    if (lane == 0) {
#pragma unroll
        for (int j = 0; j < 10; j++) { redf[wid][2 * j] = tsum[j]; redf[wid][2 * j + 1] = tsq[j]; }
    }
    __syncthreads();
    if (tid < 20)
        partial[(size_t)blockIdx.x * 20 + tid] =
            redf[0][tid] + redf[1][tid] + redf[2][tid] + redf[3][tid];
    __syncthreads();
}

// ---------------------------------------------------------------------------
// FC2: (B,10) x (2,10)^T on the block's own rows + stats partials.
// ---------------------------------------------------------------------------
DEV void fc2_layer(const float* z1, const float* fw2, float* z2, float* partial,
                   int G, float* wq2l, const float* tsA, const float* tbA,
                   float (*redf)[40])
{
    const int tid = threadIdx.x;
    if (tid < 20) wq2l[tid] = qwt(fw2[tid]);
    __syncthreads();

    float s0 = 0.f, q0 = 0.f, s1 = 0.f, q1 = 0.f;
#pragma unroll 1
    for (int tile = blockIdx.x; tile < 512; tile += G) {
        if (tid < 16) {
            int r = tile * 16 + tid;
            float a0 = 0.f, a1 = 0.f;
#pragma unroll
            for (int i = 0; i < 10; i++) {
                float xv = qact(z1[(size_t)r * 10 + i], tsA[i], tbA[i]);
                a0 = fmaf(xv, wq2l[i], a0);
                a1 = fmaf(xv, wq2l[10 + i], a1);
            }
            z2[r * 2]     = a0;
            z2[r * 2 + 1] = a1;
            s0 += a0; q0 = fmaf(a0, a0, q0);
            s1 += a1; q1 = fmaf(a1, a1, q1);
        }
    }
    const int lane = tid & 63, wid = tid >> 6;
    for (int off = 32; off > 0; off >>= 1) {
        s0 += __shfl_down(s0, off, 64); q0 += __shfl_down(q0, off, 64);
        s1 += __shfl_down(s1, off, 64); q1 += __shfl_down(q1, off, 64);
    }
    if (lane == 0) { redf[wid][0] = s0; redf[wid][1] = q0; redf[wid][2] = s1; redf[wid][3] = q1; }
    __syncthreads();
    if (tid < 4)
        partial[(size_t)blockIdx.x * 4 + tid] =
            redf[0][tid] + redf[1][tid] + redf[2][tid] + redf[3][tid];
    __syncthreads();
}

// ---------------------------------------------------------------------------
// The whole network, one cooperative kernel. 7 grid syncs (one per BN bridge).
// ---------------------------------------------------------------------------
__global__ __launch_bounds__(256, 2) void net_k(Params p)
{
    __shared__ __align__(16) signed char uni[30080];   // staging tiles / fc1 weights
    __shared__ __align__(16) int wql[400];             // packed conv weights
    __shared__ float tsA[20], tbA[20];
    __shared__ float redf[4][40];
    __shared__ double dsc[160];
    __shared__ float wq2l[20];

    cg::grid_group grid = cg::this_grid();
    const int G = p.G;

    conv_layer<1, 3, 6, 1252, 623, 624, 8, true, 1250>(p.x,  p.w1, p.y1, p.part[0], G, uni, wql, tsA, tbA, redf);
    grid.sync();
    bridge<3>(p.part[0], G, 8192.0 * 623.0, p.g[0], p.bb[0], tsA, tbA, 0.015625f, dsc);

    conv_layer<3, 5, 5, 624, 310, 312, 8, false, 0>(p.y1, p.w2, p.y2, p.part[1], G, uni, wql, tsA, tbA, redf);
    grid.sync();
    bridge<5>(p.part[1], G, 8192.0 * 310.0, p.g[1], p.bb[1], tsA, tbA, 0.015625f, dsc);

    conv_layer<5, 10, 4, 312, 154, 160, 4, false, 0>(p.y2, p.w3, p.y3, p.part[2], G, uni, wql, tsA, tbA, redf);
    grid.sync();
    bridge<10>(p.part[2], G, 8192.0 * 154.0, p.g[2], p.bb[2], tsA, tbA, 0.015625f, dsc);

    conv_layer<10, 20, 4, 160, 76, 80, 2, false, 0>(p.y3, p.w4, p.y4, p.part[3], G, uni, wql, tsA, tbA, redf);
    grid.sync();
    bridge<20>(p.part[3], G, 8192.0 * 76.0, p.g[3], p.bb[3], tsA, tbA, 0.015625f, dsc);

    conv_layer<20, 20, 4, 80, 37, 40, 1, false, 0>(p.y4, p.w5, p.y5, p.part[4], G, uni, wql, tsA, tbA, redf);
    grid.sync();
    bridge<20>(p.part[4], G, 8192.0 * 37.0, p.g[4], p.bb[4], tsA, tbA, 1.0f, dsc);  // fc1 applies 1/64 on value

    fc1_layer(p.y5, p.fw1, p.z1, p.part[5], G, (float*)uni, tsA, tbA, redf);
    grid.sync();
    bridge<10>(p.part[5], G, 8192.0, p.g[5], p.bb[5], tsA, tbA, 1.0f, dsc);

    fc2_layer(p.z1, p.fw2, p.z2, p.part[6], G, wq2l, tsA, tbA, redf);
    grid.sync();
    bridge<2>(p.part[6], G, 8192.0, p.g[6], p.bb[6], tsA, tbA, 1.0f, dsc);

    // final BN apply -> out (block's own rows)
    for (int tile = blockIdx.x; tile < 512; tile += G)
        for (int i = threadIdx.x; i < 32; i += 256) {
            int idx = tile * 32 + i;
            int c = idx & 1;
            p.out[idx] = fmaf(p.z2[idx], tsA[c], tbA[c]);
        }
}

// ---------------------------------------------------------------------------
extern "C" void kernel_launch(void* const* d_in, const int* in_sizes, int n_in,
                              void* d_out, int out_size, void* d_ws, size_t ws_size,
                              hipStream_t stream)
{
    Params p;
    p.x   = (const float*)d_in[0];
    p.w1  = (const float*)d_in[1];
    p.w2  = (const float*)d_in[2];
    p.w3  = (const float*)d_in[3];
    p.w4  = (const float*)d_in[4];
    p.w5  = (const float*)d_in[5];
    p.fw1 = (const float*)d_in[6];
    p.fw2 = (const float*)d_in[7];
    for (int i = 0; i < 7; i++) {
        p.g[i]  = (const float*)d_in[8 + 2 * i];
        p.bb[i] = (const float*)d_in[9 + 2 * i];
    }

    char* ws = (char*)d_ws;
    size_t off = 0;
    auto alloc = [&](size_t bytes) -> void* {
        void* q = ws + off;
        off += (bytes + 255) & ~(size_t)255;
        return q;
    };
    p.y1 = (short*)alloc((size_t)8192 * 3 * 624 * 2);
    p.y2 = (short*)alloc((size_t)8192 * 5 * 312 * 2);
    p.y3 = (short*)alloc((size_t)8192 * 10 * 160 * 2);
    p.y4 = (short*)alloc((size_t)8192 * 20 * 80 * 2);
    p.y5 = (short*)alloc((size_t)8192 * 20 * 40 * 2);
    p.z1 = (float*)alloc((size_t)81920 * 4);
    p.z2 = (float*)alloc((size_t)16384 * 4);
    const int pc[7] = { 6, 10, 20, 40, 40, 20, 4 };    // 2*C per layer
    for (int i = 0; i < 7; i++) p.part[i] = (float*)alloc((size_t)512 * pc[i] * 4);
    p.out = (float*)d_out;

    // grid size: must be co-resident for cooperative launch.
    int maxB = 0;
    if (hipOccupancyMaxActiveBlocksPerMultiprocessor(&maxB, net_k, 256, 0) != hipSuccess || maxB < 1)
        maxB = 1;
    int G = (maxB >= 2) ? 512 : 256;   // 256 CUs on MI355X
    p.G = G;

    void* kargs[] = { (void*)&p };
    hipLaunchCooperativeKernel((const void*)net_k, dim3(G), dim3(256), kargs, 0, stream);
}

// Round 5
// 698.503 us; speedup vs baseline: 1.1364x; 1.1364x over previous
//
#include <hip/hip_runtime.h>

#define DEV __device__ __forceinline__

// ---- quantizer helpers (exact, round-half-even matches jnp.round) ----
DEV float qwt(float w) {
    float y = fminf(fmaxf(w, -1.0f), 0.875f);
    return rintf(y * 8.0f) * 0.125f;
}
DEV int qw8i(float w) {                       // weight -> int in [-8,7]
    float y = fminf(fmaxf(w, -1.0f), 0.875f);
    return (int)rintf(y * 8.0f);
}
DEV int q8i(float x, float a, float b) {      // act -> int in [-8,7]
    float y = fmaf(x, a, b);
    y = fminf(fmaxf(y, -1.0f), 0.875f);
    return (int)rintf(y * 8.0f);
}
DEV float qact(float x, float a, float b) {
    float y = fmaf(x, a, b);
    y = fminf(fmaxf(y, -1.0f), 0.875f);
    return rintf(y * 8.0f) * 0.125f;
}

DEV int dot4(int a, int b, int c) {
#if __has_builtin(__builtin_amdgcn_sdot4)
    return __builtin_amdgcn_sdot4(a, b, c, false);
#else
    c += (int)(signed char)(a)       * (int)(signed char)(b);
    c += (int)(signed char)(a >> 8)  * (int)(signed char)(b >> 8);
    c += (int)(signed char)(a >> 16) * (int)(signed char)(b >> 16);
    c += (int)(signed char)(a >> 24) * (int)(signed char)(b >> 24);
    return c;
#endif
}
DEV unsigned alignpair(unsigned hi, unsigned lo, int bits) {
#if __has_builtin(__builtin_amdgcn_alignbit)
    return __builtin_amdgcn_alignbit(hi, lo, bits);
#else
    return bits ? ((lo >> bits) | (hi << (32 - bits))) : lo;
#endif
}

// ---------------------------------------------------------------------------
// int8/dot4 1-D strided conv (stride 2, VALID), ONE 16-row tile per block
// (grid = 512 exactly). Weights packed into LDS in the prologue. BN stats:
// per-block partials + "last block" fused deterministic fp64 finalize that
// writes the next layer's folded scale/shift (raw sc, shift — consumers
// apply the 1/64 int16 fold themselves, identical to round-3 numerics).
// ---------------------------------------------------------------------------
template<int CIN,int COUT,int K,int LINP,int LOUT,int LOUTP,int P,bool IN_FLOAT,int LIN>
__global__ __launch_bounds__(256) void conv_k(
    const void* __restrict__ in_, const float* __restrict__ w,
    const float* __restrict__ tr, short* __restrict__ out,
    float* __restrict__ partial, unsigned* __restrict__ counter,
    const float* __restrict__ gamma, const float* __restrict__ beta,
    float* __restrict__ trout, double Nstat)
{
    constexpr int KW   = (K + 3) / 4;
    constexpr int NE   = P + 2 * KW - 1;
    constexpr int ND   = (2 * (NE - 1) + 3) / 4 + 2;
    constexpr int LO_P = (LOUT + P - 1) / P;
    constexpr int GROUPS = 16 * LO_P;

    __shared__ __align__(16) signed char smem[16 * CIN * LINP + 32];
    __shared__ __align__(16) int wql[COUT * CIN * KW];
    __shared__ float ts[CIN], tb[CIN];
    __shared__ float red[4][2 * COUT];
    __shared__ double dsc[8 * COUT];
    __shared__ int isLast;

    const int tid = threadIdx.x;
    const int bid = blockIdx.x;
    const int r0  = bid * 16;

    // pack quantized weights into LDS dwords (byte u of dword j = tap 4j+u)
    for (int i = tid; i < COUT * CIN * KW; i += 256) {
        int j = i % KW, cc = i / KW;
        unsigned rr = 0;
        for (int u = 0; u < 4; u++) {
            int k = 4 * j + u;
            int bv = (k < K) ? (qw8i(w[cc * K + k]) & 0xff) : 0;
            rr |= (unsigned)bv << (8 * u);
        }
        wql[i] = (int)rr;
    }
    if constexpr (!IN_FLOAT) {
        if (tid < CIN) {
            ts[tid] = tr[tid] * 0.015625f;   // fold /64 of int16 storage
            tb[tid] = tr[CIN + tid];
        }
    }
    __syncthreads();

    // ---- stage 16 rows: global -> quantized int8 LDS ----
    if constexpr (IN_FLOAT) {
        constexpr int CH = LIN / 2;
        const float2* gp = (const float2*)in_;
        for (int c = tid; c < 16 * CH; c += 256) {
            int r = c / CH, rem = c - r * CH;
            float2 v = gp[(size_t)(r0 + r) * CH + rem];
            int b0 = q8i(v.x, 1.f, 0.f) & 0xff;
            int b1 = q8i(v.y, 1.f, 0.f) & 0xff;
            *(unsigned short*)(smem + r * LINP + rem * 2) =
                (unsigned short)(b0 | (b1 << 8));
        }
    } else {
        constexpr int CH  = CIN * LINP / 8;
        constexpr int CHC = LINP / 8;
        const int4* gp = (const int4*)((const short*)in_ + (size_t)r0 * CIN * LINP);
        for (int c = tid; c < 16 * CH; c += 256) {
            int rem = c % CH;
            int ci = rem / CHC;
            float a = ts[ci], bo = tb[ci];
            int4 v = gp[c];
            int vs[4] = { v.x, v.y, v.z, v.w };
            unsigned pk[2];
#pragma unroll
            for (int u = 0; u < 2; u++) {
                unsigned pp = 0;
#pragma unroll
                for (int j = 0; j < 2; j++) {
                    int word = vs[u * 2 + j];
                    int b0 = q8i((float)(short)(word & 0xffff), a, bo) & 0xff;
                    int b1 = q8i((float)(short)(word >> 16),    a, bo) & 0xff;
                    pp |= (unsigned)(b0 | (b1 << 8)) << (16 * j);
                }
                pk[u] = pp;
            }
            ((uint2*)smem)[c] = make_uint2(pk[0], pk[1]);
        }
    }
    __syncthreads();

    float tsum[COUT], tsq[COUT];
#pragma unroll
    for (int c = 0; c < COUT; c++) { tsum[c] = 0.f; tsq[c] = 0.f; }

    // ---- compute ----
#pragma unroll 1
    for (int g = tid; g < GROUPS; g += 256) {
        int r = g / LO_P;
        int l0   = (g - r * LO_P) * P;
        int pact = min(P, LOUT - l0);

        int acc[COUT][P];
#pragma unroll
        for (int co = 0; co < COUT; co++)
#pragma unroll
            for (int p = 0; p < P; p++) acc[co][p] = 0;

        const int ibase = r * CIN * LINP + 2 * l0;
        const int sh    = (P % 2 == 0) ? 0 : (ibase & 3);

        for (int ci = 0; ci < CIN; ci++) {
            const int* sp = (const int*)smem + ((ci * LINP + (ibase & ~3)) >> 2);
            int d[ND];
#pragma unroll
            for (int j = 0; j < ND; j++) d[j] = sp[j];
            int e[NE];
#pragma unroll
            for (int i = 0; i < NE; i++) {
                int off = sh + 2 * i;
                e[i] = (int)alignpair((unsigned)d[off / 4 + 1], (unsigned)d[off / 4], (off & 3) * 8);
            }
#pragma unroll
            for (int co = 0; co < COUT; co++) {
#pragma unroll
                for (int j = 0; j < KW; j++) {
                    int wv = wql[(co * CIN + ci) * KW + j];
#pragma unroll
                    for (int p = 0; p < P; p++)
                        acc[co][p] = dot4(e[p + 2 * j], wv, acc[co][p]);
                }
            }
        }

        const size_t ob = (size_t)(r0 + r) * COUT * LOUTP + l0;
#pragma unroll
        for (int co = 0; co < COUT; co++) {
            if (pact == P) {
                short tmp[P];
#pragma unroll
                for (int p = 0; p < P; p++) {
                    tmp[p] = (short)acc[co][p];
                    float v = (float)acc[co][p] * 0.015625f;
                    tsum[co] += v;
                    tsq[co]   = fmaf(v, v, tsq[co]);
                }
                short* op = &out[ob + (size_t)co * LOUTP];
                if constexpr (P == 1) {
                    op[0] = tmp[0];
                } else if constexpr (P == 2) {
                    *(short2*)op = make_short2(tmp[0], tmp[1]);
                } else if constexpr (P == 4) {
                    *(short4*)op = make_short4(tmp[0], tmp[1], tmp[2], tmp[3]);
                } else if constexpr (P == 8) {
                    *(short4*)op       = make_short4(tmp[0], tmp[1], tmp[2], tmp[3]);
                    *(short4*)(op + 4) = make_short4(tmp[4], tmp[5], tmp[6], tmp[7]);
                }
            } else {
#pragma unroll
                for (int p = 0; p < P; p++) {
                    if (p < pact) {
                        out[ob + (size_t)co * LOUTP + p] = (short)acc[co][p];
                        float v = (float)acc[co][p] * 0.015625f;
                        tsum[co] += v;
                        tsq[co]   = fmaf(v, v, tsq[co]);
                    }
                }
            }
        }
    }

    // ---- block stat reduction -> partial ----
    const int lane = tid & 63, wid = tid >> 6;
#pragma unroll
    for (int co = 0; co < COUT; co++) {
        float s = tsum[co], q = tsq[co];
        for (int off = 32; off > 0; off >>= 1) {
            s += __shfl_down(s, off, 64);
            q += __shfl_down(q, off, 64);
        }
        if (lane == 0) { red[wid][2 * co] = s; red[wid][2 * co + 1] = q; }
    }
    __syncthreads();
    if (tid < 2 * COUT)
        partial[(size_t)bid * (2 * COUT) + tid] =
            red[0][tid] + red[1][tid] + red[2][tid] + red[3][tid];

    // ---- fused finalize: last arriving block reduces all partials ----
    __threadfence();
    if (tid == 0) isLast = (atomicAdd(counter, 1u) == 511u);
    __syncthreads();
    if (isLast) {
        __threadfence();
        if (tid < 2 * COUT * 4) {
            int slot = tid >> 2, ch = tid & 3;
            double s = 0.0;
            for (int g2 = ch; g2 < 512; g2 += 4)
                s += (double)partial[(size_t)g2 * (2 * COUT) + slot];
            dsc[tid] = s;
        }
        __syncthreads();
        if (tid < COUT) {
            double S = dsc[8 * tid]     + dsc[8 * tid + 1] + dsc[8 * tid + 2] + dsc[8 * tid + 3];
            double Q = dsc[8 * tid + 4] + dsc[8 * tid + 5] + dsc[8 * tid + 6] + dsc[8 * tid + 7];
            double mean = S / Nstat;
            double var  = Q / Nstat - mean * mean;
            double inv  = 1.0 / sqrt(var + 1e-5);
            double sc   = (double)gamma[tid] * inv;
            trout[tid]        = (float)sc;
            trout[COUT + tid] = (float)((double)beta[tid] - mean * sc);
        }
    }
}

// ---------------------------------------------------------------------------
// FC1: (B,740)x(10,740)^T, one wave per row, 16 rows per block (grid 512),
// fused last-block finalize writes tr7.
// ---------------------------------------------------------------------------
__global__ __launch_bounds__(256) void fc1_k(
    const short* __restrict__ y5, const float* __restrict__ fw1,
    const float* __restrict__ tr, float* __restrict__ z1,
    float* __restrict__ partial, unsigned* __restrict__ counter,
    const float* __restrict__ gamma, const float* __restrict__ beta,
    float* __restrict__ trout)
{
    __shared__ float wq[7400];
    __shared__ float ts[20], tb[20];
    __shared__ float red[4][20];
    __shared__ double dsc[80];
    __shared__ int isLast;

    const int tid = threadIdx.x;
    const int bid = blockIdx.x;
    for (int i = tid; i < 7400; i += 256) wq[i] = qwt(fw1[i]);
    if (tid < 20) { ts[tid] = tr[tid]; tb[tid] = tr[20 + tid]; }
    __syncthreads();

    const int lane = tid & 63, wid = tid >> 6;
    float tsum[10], tsq[10];
#pragma unroll
    for (int j = 0; j < 10; j++) { tsum[j] = 0.f; tsq[j] = 0.f; }

#pragma unroll 1
    for (int pass = 0; pass < 4; pass++) {
        int r = bid * 16 + pass * 4 + wid;
        const short* xr = y5 + (size_t)r * 800;   // 20ch x 40 padded
        float acc[10];
#pragma unroll
        for (int j = 0; j < 10; j++) acc[j] = 0.f;
#pragma unroll 1
        for (int f = lane; f < 740; f += 64) {
            int c = f / 37, pos = f - c * 37;
            float xv = qact((float)xr[c * 40 + pos] * 0.015625f, ts[c], tb[c]);
#pragma unroll
            for (int j = 0; j < 10; j++) acc[j] = fmaf(xv, wq[j * 740 + f], acc[j]);
        }
#pragma unroll
        for (int j = 0; j < 10; j++) {
            float v = acc[j];
            for (int off = 1; off < 64; off <<= 1) v += __shfl_xor(v, off, 64);
            tsum[j] += v; tsq[j] = fmaf(v, v, tsq[j]);
            if (lane == j) z1[(size_t)r * 10 + j] = v;
        }
    }
    if (lane == 0) {
#pragma unroll
        for (int j = 0; j < 10; j++) { red[wid][2 * j] = tsum[j]; red[wid][2 * j + 1] = tsq[j]; }
    }
    __syncthreads();
    if (tid < 20)
        partial[(size_t)bid * 20 + tid] =
            red[0][tid] + red[1][tid] + red[2][tid] + red[3][tid];

    __threadfence();
    if (tid == 0) isLast = (atomicAdd(counter, 1u) == 511u);
    __syncthreads();
    if (isLast) {
        __threadfence();
        if (tid < 80) {
            int slot = tid >> 2, ch = tid & 3;
            double s = 0.0;
            for (int g2 = ch; g2 < 512; g2 += 4)
                s += (double)partial[(size_t)g2 * 20 + slot];
            dsc[tid] = s;
        }
        __syncthreads();
        if (tid < 10) {
            double N = 8192.0;
            double S = dsc[8 * tid]     + dsc[8 * tid + 1] + dsc[8 * tid + 2] + dsc[8 * tid + 3];
            double Q = dsc[8 * tid + 4] + dsc[8 * tid + 5] + dsc[8 * tid + 6] + dsc[8 * tid + 7];
            double mean = S / N;
            double var  = Q / N - mean * mean;
            double inv  = 1.0 / sqrt(var + 1e-5);
            double sc   = (double)gamma[tid] * inv;
            trout[tid]      = (float)sc;
            trout[10 + tid] = (float)((double)beta[tid] - mean * sc);
        }
    }
}

// ---------------------------------------------------------------------------
// FC2 fused single-block: z2 rows (LDS) + stats + final BN apply -> out.
// ---------------------------------------------------------------------------
__global__ __launch_bounds__(256) void fc2_fused_k(
    const float* __restrict__ z1, const float* __restrict__ fw2,
    const float* __restrict__ tr7,
    const float* __restrict__ g7, const float* __restrict__ b7,
    float* __restrict__ outp)
{
    __shared__ float zbuf[16384];
    __shared__ float ts7[10], tb7[10], wq2[20];
    __shared__ float fr[4][4];
    __shared__ float tr8[4];

    const int tid = threadIdx.x;
    const int lane = tid & 63, wid = tid >> 6;
    const int B = 8192;

    if (tid < 20) wq2[tid] = qwt(fw2[tid]);
    if (tid < 10) { ts7[tid] = tr7[tid]; tb7[tid] = tr7[10 + tid]; }
    __syncthreads();

    float s0 = 0.f, q0 = 0.f, s1 = 0.f, q1 = 0.f;
#pragma unroll 1
    for (int r = tid; r < B; r += 256) {
        float a0 = 0.f, a1 = 0.f;
#pragma unroll
        for (int i = 0; i < 10; i++) {
            float x = qact(z1[(size_t)r * 10 + i], ts7[i], tb7[i]);
            a0 = fmaf(x, wq2[i], a0);
            a1 = fmaf(x, wq2[10 + i], a1);
        }
        zbuf[r * 2]     = a0;
        zbuf[r * 2 + 1] = a1;
        s0 += a0; q0 = fmaf(a0, a0, q0);
        s1 += a1; q1 = fmaf(a1, a1, q1);
    }
    for (int off = 32; off > 0; off >>= 1) {
        s0 += __shfl_down(s0, off, 64); q0 += __shfl_down(q0, off, 64);
        s1 += __shfl_down(s1, off, 64); q1 += __shfl_down(q1, off, 64);
    }
    if (lane == 0) { fr[wid][0] = s0; fr[wid][1] = q0; fr[wid][2] = s1; fr[wid][3] = q1; }
    __syncthreads();
    if (tid < 2) {
        double S = 0.0, Q = 0.0;
        for (int w = 0; w < 4; w++) { S += (double)fr[w][2 * tid]; Q += (double)fr[w][2 * tid + 1]; }
        double N = (double)B;
        double mean = S / N;
        double var  = Q / N - mean * mean;
        double inv  = 1.0 / sqrt(var + 1e-5);
        double sc   = (double)g7[tid] * inv;
        tr8[tid]     = (float)sc;
        tr8[2 + tid] = (float)((double)b7[tid] - mean * sc);
    }
    __syncthreads();
    for (int i = tid; i < 2 * B; i += 256) {
        int c = i & 1;
        outp[i] = fmaf(zbuf[i], tr8[c], tr8[2 + c]);
    }
}

// ---------------------------------------------------------------------------
extern "C" void kernel_launch(void* const* d_in, const int* in_sizes, int n_in,
                              void* d_out, int out_size, void* d_ws, size_t ws_size,
                              hipStream_t stream)
{
    const float* x   = (const float*)d_in[0];
    const float* w1  = (const float*)d_in[1];
    const float* w2  = (const float*)d_in[2];
    const float* w3  = (const float*)d_in[3];
    const float* w4  = (const float*)d_in[4];
    const float* w5  = (const float*)d_in[5];
    const float* fw1 = (const float*)d_in[6];
    const float* fw2 = (const float*)d_in[7];
    const float *g[7], *bb[7];
    for (int i = 0; i < 7; i++) { g[i] = (const float*)d_in[8 + 2 * i]; bb[i] = (const float*)d_in[9 + 2 * i]; }

    char* ws = (char*)d_ws;
    size_t off = 0;
    auto alloc = [&](size_t bytes) -> void* {
        void* q = ws + off;
        off += (bytes + 255) & ~(size_t)255;
        return q;
    };
    short* y1 = (short*)alloc((size_t)8192 * 3 * 624 * 2);
    short* y2 = (short*)alloc((size_t)8192 * 5 * 312 * 2);
    short* y3 = (short*)alloc((size_t)8192 * 10 * 160 * 2);
    short* y4 = (short*)alloc((size_t)8192 * 20 * 80 * 2);
    short* y5 = (short*)alloc((size_t)8192 * 20 * 40 * 2);
    float* z1 = (float*)alloc((size_t)81920 * 4);
    float* part[6];
    const int pc[6] = { 6, 10, 20, 40, 40, 20 };    // 2*C per layer
    for (int i = 0; i < 6; i++) part[i] = (float*)alloc((size_t)512 * pc[i] * 4);
    float* tr2 = (float*)alloc(256); float* tr3 = (float*)alloc(256);
    float* tr4 = (float*)alloc(256); float* tr5 = (float*)alloc(256);
    float* tr6 = (float*)alloc(256); float* tr7 = (float*)alloc(256);
    unsigned* cnt = (unsigned*)alloc(64);

    hipMemsetAsync(cnt, 0, 64, stream);

    conv_k<1, 3, 6, 1252, 623, 624, 8, true, 1250><<<512, 256, 0, stream>>>(
        x, w1, nullptr, y1, part[0], cnt + 0, g[0], bb[0], tr2, 8192.0 * 623.0);
    conv_k<3, 5, 5, 624, 310, 312, 8, false, 0><<<512, 256, 0, stream>>>(
        y1, w2, tr2, y2, part[1], cnt + 1, g[1], bb[1], tr3, 8192.0 * 310.0);
    conv_k<5, 10, 4, 312, 154, 160, 4, false, 0><<<512, 256, 0, stream>>>(
        y2, w3, tr3, y3, part[2], cnt + 2, g[2], bb[2], tr4, 8192.0 * 154.0);
    conv_k<10, 20, 4, 160, 76, 80, 2, false, 0><<<512, 256, 0, stream>>>(
        y3, w4, tr4, y4, part[3], cnt + 3, g[3], bb[3], tr5, 8192.0 * 76.0);
    conv_k<20, 20, 4, 80, 37, 40, 1, false, 0><<<512, 256, 0, stream>>>(
        y4, w5, tr5, y5, part[4], cnt + 4, g[4], bb[4], tr6, 8192.0 * 37.0);
    fc1_k<<<512, 256, 0, stream>>>(
        y5, fw1, tr6, z1, part[5], cnt + 5, g[5], bb[5], tr7);
    fc2_fused_k<<<1, 256, 0, stream>>>(z1, fw2, tr7, g[6], bb[6], (float*)d_out);
}

// Round 6
// 303.733 us; speedup vs baseline: 2.6135x; 2.2997x over previous
//
#include <hip/hip_runtime.h>

#define DEV __device__ __forceinline__

// ---- quantizer helpers (exact, round-half-even matches jnp.round) ----
DEV float qwt(float w) {
    float y = fminf(fmaxf(w, -1.0f), 0.875f);
    return rintf(y * 8.0f) * 0.125f;
}
DEV int qw8i(float w) {                       // weight -> int in [-8,7]
    float y = fminf(fmaxf(w, -1.0f), 0.875f);
    return (int)rintf(y * 8.0f);
}
DEV int q8i(float x, float a, float b) {      // act -> int in [-8,7]
    float y = fmaf(x, a, b);
    y = fminf(fmaxf(y, -1.0f), 0.875f);
    return (int)rintf(y * 8.0f);
}
DEV float qact(float x, float a, float b) {
    float y = fmaf(x, a, b);
    y = fminf(fmaxf(y, -1.0f), 0.875f);
    return rintf(y * 8.0f) * 0.125f;
}

DEV int dot4(int a, int b, int c) {
#if __has_builtin(__builtin_amdgcn_sdot4)
    return __builtin_amdgcn_sdot4(a, b, c, false);
#else
    c += (int)(signed char)(a)       * (int)(signed char)(b);
    c += (int)(signed char)(a >> 8)  * (int)(signed char)(b >> 8);
    c += (int)(signed char)(a >> 16) * (int)(signed char)(b >> 16);
    c += (int)(signed char)(a >> 24) * (int)(signed char)(b >> 24);
    return c;
#endif
}
DEV unsigned alignpair(unsigned hi, unsigned lo, int bits) {
#if __has_builtin(__builtin_amdgcn_alignbit)
    return __builtin_amdgcn_alignbit(hi, lo, bits);
#else
    return bits ? ((lo >> bits) | (hi << (32 - bits))) : lo;
#endif
}

// ---------------------------------------------------------------------------
// Pack all conv weights: float OIHW -> int8x4 dwords (value*8), zero-padded
// beyond K. Layout: wq[(co*CIN+ci)*KW + j], byte u = tap 4j+u. Global so the
// conv kernels read them via wave-uniform scalar loads (s_load, K$-cached).
// ---------------------------------------------------------------------------
DEV void pack_layer(const float* w, int* o, int CIN, int COUT, int K, int t) {
    int KW = (K + 3) / 4;
    for (int i = t; i < COUT * CIN * KW; i += 256) {
        int j = i % KW, cc = i / KW;
        unsigned r = 0;
        for (int u = 0; u < 4; u++) {
            int k = 4 * j + u;
            int b = (k < K) ? (qw8i(w[cc * K + k]) & 0xff) : 0;
            r |= (unsigned)b << (8 * u);
        }
        o[i] = (int)r;
    }
}
__global__ __launch_bounds__(256) void pack_k(
    const float* w1, const float* w2, const float* w3, const float* w4, const float* w5,
    int* o1, int* o2, int* o3, int* o4, int* o5)
{
    int t = threadIdx.x;
    pack_layer(w1, o1, 1, 3, 6, t);
    pack_layer(w2, o2, 3, 5, 5, t);
    pack_layer(w3, o3, 5, 10, 4, t);
    pack_layer(w4, o4, 10, 20, 4, t);
    pack_layer(w5, o5, 20, 20, 4, t);
}

// ---------------------------------------------------------------------------
// int8/dot4 1-D strided conv (stride 2, VALID).
// Stage R rows -> int8 (x8) LDS with quantize(a*x+b) applied once per elem.
// Compute: per thread, P consecutive outputs; windows built from aligned
// dword LDS reads + alignbit; sdot4 against scalar-loaded packed weights.
// Output short = int acc (value*64, exact). BN sum/sumsq partials per block.
// ---------------------------------------------------------------------------
template<int CIN,int COUT,int K,int LINP,int LOUT,int LOUTP,int P,int R,bool IN_FLOAT,int LIN=0>
__global__ __launch_bounds__(256) void conv_k(
    const void* __restrict__ in_, const int* __restrict__ wqi,
    const float* __restrict__ tr, short* __restrict__ out,
    float* __restrict__ partial, int B)
{
    constexpr int KW   = (K + 3) / 4;
    constexpr int NE   = P + 2 * KW - 1;
    constexpr int ND   = (2 * (NE - 1) + 3) / 4 + 2;
    constexpr int LO_P = (LOUT + P - 1) / P;
    constexpr int GROUPS = R * LO_P;

    __shared__ __align__(16) signed char smem[R * CIN * LINP + 32];
    __shared__ float ts[CIN > 0 ? CIN : 1], tb[CIN > 0 ? CIN : 1];
    __shared__ float red[4][2 * COUT];

    const int tid = threadIdx.x;

    if constexpr (!IN_FLOAT) {
        if (tid < CIN) {
            ts[tid] = tr[tid] * 0.015625f;   // fold /64 of int16 storage
            tb[tid] = tr[CIN + tid];
        }
        __syncthreads();
    }

    const int r0   = blockIdx.x * R;
    const int rcnt = min(R, B - r0);

    // ---- stage: global -> quantized int8 LDS ----
    if constexpr (IN_FLOAT) {
        constexpr int CH = LIN / 2;
        const float2* gp = (const float2*)in_;
        for (int c = tid; c < rcnt * CH; c += 256) {
            int r = c / CH, rem = c - r * CH;
            float2 v = gp[(size_t)(r0 + r) * CH + rem];
            int b0 = q8i(v.x, 1.f, 0.f) & 0xff;
            int b1 = q8i(v.y, 1.f, 0.f) & 0xff;
            *(unsigned short*)(smem + r * LINP + rem * 2) =
                (unsigned short)(b0 | (b1 << 8));
        }
    } else {
        constexpr int CH  = CIN * LINP / 8;
        constexpr int CHC = LINP / 8;
        const int4* gp = (const int4*)((const short*)in_ + (size_t)r0 * CIN * LINP);
        for (int c = tid; c < rcnt * CH; c += 256) {
            int rem = c % CH;
            int ci = rem / CHC;
            float a = ts[ci], bo = tb[ci];
            int4 v = gp[c];
            int vs[4] = { v.x, v.y, v.z, v.w };
            unsigned pk[2];
#pragma unroll
            for (int u = 0; u < 2; u++) {
                unsigned pp = 0;
#pragma unroll
                for (int j = 0; j < 2; j++) {
                    int word = vs[u * 2 + j];
                    int b0 = q8i((float)(short)(word & 0xffff), a, bo) & 0xff;
                    int b1 = q8i((float)(short)(word >> 16),    a, bo) & 0xff;
                    pp |= (unsigned)(b0 | (b1 << 8)) << (16 * j);
                }
                pk[u] = pp;
            }
            ((uint2*)smem)[c] = make_uint2(pk[0], pk[1]);
        }
    }
    __syncthreads();

    float tsum[COUT], tsq[COUT];
#pragma unroll
    for (int c = 0; c < COUT; c++) { tsum[c] = 0.f; tsq[c] = 0.f; }

    // ---- compute ----
#pragma unroll 1
    for (int g = tid; g < GROUPS; g += 256) {
        int r = g / LO_P;
        if (r >= rcnt) continue;
        int l0   = (g - r * LO_P) * P;
        int pact = min(P, LOUT - l0);

        int acc[COUT][P];
#pragma unroll
        for (int co = 0; co < COUT; co++)
#pragma unroll
            for (int p = 0; p < P; p++) acc[co][p] = 0;

        const int ibase = r * CIN * LINP + 2 * l0;
        const int sh    = (P % 2 == 0) ? 0 : (ibase & 3);

        for (int ci = 0; ci < CIN; ci++) {
            const int* sp = (const int*)smem + ((ci * LINP + (ibase & ~3)) >> 2);
            int d[ND];
#pragma unroll
            for (int j = 0; j < ND; j++) d[j] = sp[j];
            int e[NE];
#pragma unroll
            for (int i = 0; i < NE; i++) {
                int off = sh + 2 * i;
                e[i] = (int)alignpair((unsigned)d[off / 4 + 1], (unsigned)d[off / 4], (off & 3) * 8);
            }
#pragma unroll
            for (int co = 0; co < COUT; co++) {
#pragma unroll
                for (int j = 0; j < KW; j++) {
                    int wv = wqi[(co * CIN + ci) * KW + j];
#pragma unroll
                    for (int p = 0; p < P; p++)
                        acc[co][p] = dot4(e[p + 2 * j], wv, acc[co][p]);
                }
            }
        }

        const size_t ob = (size_t)(r0 + r) * COUT * LOUTP + l0;
#pragma unroll
        for (int co = 0; co < COUT; co++) {
            if (pact == P) {
                short tmp[P];
#pragma unroll
                for (int p = 0; p < P; p++) {
                    tmp[p] = (short)acc[co][p];
                    float v = (float)acc[co][p] * 0.015625f;
                    tsum[co] += v;
                    tsq[co]   = fmaf(v, v, tsq[co]);
                }
                short* op = &out[ob + (size_t)co * LOUTP];
                if constexpr (P == 1) {
                    op[0] = tmp[0];
                } else if constexpr (P == 2) {
                    *(short2*)op = make_short2(tmp[0], tmp[1]);
                } else if constexpr (P == 4) {
                    *(short4*)op = make_short4(tmp[0], tmp[1], tmp[2], tmp[3]);
                } else if constexpr (P == 8) {
                    *(short4*)op       = make_short4(tmp[0], tmp[1], tmp[2], tmp[3]);
                    *(short4*)(op + 4) = make_short4(tmp[4], tmp[5], tmp[6], tmp[7]);
                }
            } else {
#pragma unroll
                for (int p = 0; p < P; p++) {
                    if (p < pact) {
                        out[ob + (size_t)co * LOUTP + p] = (short)acc[co][p];
                        float v = (float)acc[co][p] * 0.015625f;
                        tsum[co] += v;
                        tsq[co]   = fmaf(v, v, tsq[co]);
                    }
                }
            }
        }
    }

    const int lane = tid & 63, wid = tid >> 6;
#pragma unroll
    for (int co = 0; co < COUT; co++) {
        float s = tsum[co], q = tsq[co];
        for (int off = 32; off > 0; off >>= 1) {
            s += __shfl_down(s, off, 64);
            q += __shfl_down(q, off, 64);
        }
        if (lane == 0) { red[wid][2 * co] = s; red[wid][2 * co + 1] = q; }
    }
    __syncthreads();
    if (tid < 2 * COUT) {
        float v = red[0][tid] + red[1][tid] + red[2][tid] + red[3][tid];
        partial[(size_t)blockIdx.x * (2 * COUT) + tid] = v;
    }
}

// ---------------------------------------------------------------------------
// Finalize BN stats -> folded scale/shift
// ---------------------------------------------------------------------------
__global__ __launch_bounds__(256) void finalize_k(
    const float* __restrict__ partial, int G, int C, double N,
    const float* __restrict__ gamma, const float* __restrict__ beta,
    float* __restrict__ trout)
{
    const int c = blockIdx.x;
    double s = 0.0, q = 0.0;
    for (int g = threadIdx.x; g < G; g += 256) {
        s += (double)partial[(size_t)g * 2 * C + 2 * c];
        q += (double)partial[(size_t)g * 2 * C + 2 * c + 1];
    }
    for (int off = 32; off > 0; off >>= 1) {
        s += __shfl_down(s, off, 64);
        q += __shfl_down(q, off, 64);
    }
    __shared__ double rs[4], rq[4];
    int lane = threadIdx.x & 63, wid = threadIdx.x >> 6;
    if (lane == 0) { rs[wid] = s; rq[wid] = q; }
    __syncthreads();
    if (threadIdx.x == 0) {
        double S = rs[0] + rs[1] + rs[2] + rs[3];
        double Q = rq[0] + rq[1] + rq[2] + rq[3];
        double mean = S / N;
        double var  = Q / N - mean * mean;
        double inv  = 1.0 / sqrt(var + 1e-5);
        double sc   = (double)gamma[c] * inv;
        trout[c]     = (float)sc;
        trout[C + c] = (float)((double)beta[c] - mean * sc);
    }
}

// ---------------------------------------------------------------------------
// FC1: (B,740)x(10,740)^T, one wave per row; y5 is (B,20,40) padded shorts.
// grid 2048 -> single row-pass per wave.
// ---------------------------------------------------------------------------
__global__ __launch_bounds__(256) void fc1_k(
    const short* __restrict__ y5, const float* __restrict__ fw1,
    const float* __restrict__ tr, float* __restrict__ z1,
    float* __restrict__ partial, int B)
{
    __shared__ float wq[7400];
    __shared__ float ts[20], tb[20];
    __shared__ float red[4][20];
    const int tid = threadIdx.x;
    for (int i = tid; i < 7400; i += 256) wq[i] = qwt(fw1[i]);
    if (tid < 20) { ts[tid] = tr[tid]; tb[tid] = tr[20 + tid]; }
    __syncthreads();

    const int lane = tid & 63, wid = tid >> 6;
    float tsum[10], tsq[10];
#pragma unroll
    for (int j = 0; j < 10; j++) { tsum[j] = 0.f; tsq[j] = 0.f; }

#pragma unroll 1
    for (int r = blockIdx.x * 4 + wid; r < B; r += gridDim.x * 4) {
        const short* xr = y5 + (size_t)r * 800;
        float acc[10];
#pragma unroll
        for (int j = 0; j < 10; j++) acc[j] = 0.f;
#pragma unroll 1
        for (int f = lane; f < 740; f += 64) {
            int c = f / 37, pos = f - c * 37;
            float x = qact((float)xr[c * 40 + pos] * 0.015625f, ts[c], tb[c]);
#pragma unroll
            for (int j = 0; j < 10; j++) acc[j] = fmaf(x, wq[j * 740 + f], acc[j]);
        }
#pragma unroll
        for (int j = 0; j < 10; j++) {
            float v = acc[j];
            for (int off = 1; off < 64; off <<= 1) v += __shfl_xor(v, off, 64);
            tsum[j] += v; tsq[j] = fmaf(v, v, tsq[j]);
            if (lane == j) z1[(size_t)r * 10 + j] = v;
        }
    }
    if (lane == 0) {
#pragma unroll
        for (int j = 0; j < 10; j++) { red[wid][2 * j] = tsum[j]; red[wid][2 * j + 1] = tsq[j]; }
    }
    __syncthreads();
    if (tid < 20) {
        float v = red[0][tid] + red[1][tid] + red[2][tid] + red[3][tid];
        partial[(size_t)blockIdx.x * 20 + tid] = v;
    }
}

// ---------------------------------------------------------------------------
// FC2 fused single-block: reduce fc1 partials -> tr7, compute z2 (LDS),
// z2 stats -> tr8, apply -> out.  One dispatch replaces 4.
// ---------------------------------------------------------------------------
__global__ __launch_bounds__(256) void fc2_fused_k(
    const float* __restrict__ z1, const float* __restrict__ fw2,
    const float* __restrict__ part6, int G6,
    const float* __restrict__ g6, const float* __restrict__ b6,
    const float* __restrict__ g7, const float* __restrict__ b7,
    float* __restrict__ outp, int B)
{
    __shared__ float zbuf[16384];
    __shared__ double dred[4][20];
    __shared__ double dtot[20];
    __shared__ float ts7[10], tb7[10], wq2[20];
    __shared__ float fr[4][4];
    __shared__ float tr8[4];

    const int tid = threadIdx.x;
    const int lane = tid & 63, wid = tid >> 6;

    // prologue: reduce fc1 partials (G6 x 20) in doubles
    double ls[20];
#pragma unroll
    for (int c = 0; c < 20; c++) ls[c] = 0.0;
    for (int g = tid; g < G6; g += 256) {
#pragma unroll
        for (int c = 0; c < 20; c++) ls[c] += (double)part6[(size_t)g * 20 + c];
    }
#pragma unroll
    for (int c = 0; c < 20; c++) {
        double v = ls[c];
        for (int off = 32; off > 0; off >>= 1) v += __shfl_down(v, off, 64);
        if (lane == 0) dred[wid][c] = v;
    }
    if (tid < 20) wq2[tid] = qwt(fw2[tid]);
    __syncthreads();
    if (tid < 20) dtot[tid] = dred[0][tid] + dred[1][tid] + dred[2][tid] + dred[3][tid];
    __syncthreads();
    if (tid < 10) {
        double N = (double)B;
        double mean = dtot[2 * tid] / N;
        double var  = dtot[2 * tid + 1] / N - mean * mean;
        double inv  = 1.0 / sqrt(var + 1e-5);
        double sc   = (double)g6[tid] * inv;
        ts7[tid] = (float)sc;
        tb7[tid] = (float)((double)b6[tid] - mean * sc);
    }
    __syncthreads();

    // main: z2 rows + stats
    float s0 = 0.f, q0 = 0.f, s1 = 0.f, q1 = 0.f;
#pragma unroll 1
    for (int r = tid; r < B; r += 256) {
        float a0 = 0.f, a1 = 0.f;
#pragma unroll
        for (int i = 0; i < 10; i++) {
            float x = qact(z1[(size_t)r * 10 + i], ts7[i], tb7[i]);
            a0 = fmaf(x, wq2[i], a0);
            a1 = fmaf(x, wq2[10 + i], a1);
        }
        zbuf[r * 2]     = a0;
        zbuf[r * 2 + 1] = a1;
        s0 += a0; q0 = fmaf(a0, a0, q0);
        s1 += a1; q1 = fmaf(a1, a1, q1);
    }
    for (int off = 32; off > 0; off >>= 1) {
        s0 += __shfl_down(s0, off, 64); q0 += __shfl_down(q0, off, 64);
        s1 += __shfl_down(s1, off, 64); q1 += __shfl_down(q1, off, 64);
    }
    if (lane == 0) { fr[wid][0] = s0; fr[wid][1] = q0; fr[wid][2] = s1; fr[wid][3] = q1; }
    __syncthreads();
    if (tid < 2) {
        double S = 0.0, Q = 0.0;
        for (int w = 0; w < 4; w++) { S += (double)fr[w][2 * tid]; Q += (double)fr[w][2 * tid + 1]; }
        double N = (double)B;
        double mean = S / N;
        double var  = Q / N - mean * mean;
        double inv  = 1.0 / sqrt(var + 1e-5);
        double sc   = (double)g7[tid] * inv;
        tr8[tid]     = (float)sc;
        tr8[2 + tid] = (float)((double)b7[tid] - mean * sc);
    }
    __syncthreads();
    for (int i = tid; i < 2 * B; i += 256) {
        int c = i & 1;
        outp[i] = fmaf(zbuf[i], tr8[c], tr8[2 + c]);
    }
}

// ---------------------------------------------------------------------------
extern "C" void kernel_launch(void* const* d_in, const int* in_sizes, int n_in,
                              void* d_out, int out_size, void* d_ws, size_t ws_size,
                              hipStream_t stream)
{
    const float* x   = (const float*)d_in[0];
    const float* w1  = (const float*)d_in[1];
    const float* w2  = (const float*)d_in[2];
    const float* w3  = (const float*)d_in[3];
    const float* w4  = (const float*)d_in[4];
    const float* w5  = (const float*)d_in[5];
    const float* fw1 = (const float*)d_in[6];
    const float* fw2 = (const float*)d_in[7];
    const float *g[7], *bb[7];
    for (int i = 0; i < 7; i++) { g[i] = (const float*)d_in[8 + 2 * i]; bb[i] = (const float*)d_in[9 + 2 * i]; }

    char* ws = (char*)d_ws;
    size_t off = 0;
    auto alloc = [&](size_t bytes) -> void* {
        void* q = ws + off;
        off += (bytes + 255) & ~(size_t)255;
        return q;
    };
    short* y1 = (short*)alloc((size_t)8192 * 3 * 624 * 2);
    short* y2 = (short*)alloc((size_t)8192 * 5 * 312 * 2);
    short* y3 = (short*)alloc((size_t)8192 * 10 * 160 * 2);
    short* y4 = (short*)alloc((size_t)8192 * 20 * 80 * 2);
    short* y5 = (short*)alloc((size_t)8192 * 20 * 40 * 2);
    float* z1 = (float*)alloc((size_t)81920 * 4);
    float* partial = (float*)alloc((size_t)81920 * 4);
    int*   wp1 = (int*)alloc(64);   int* wp2 = (int*)alloc(256);
    int*   wp3 = (int*)alloc(256);  int* wp4 = (int*)alloc(1024);
    int*   wp5 = (int*)alloc(2048);
    float* tr2 = (float*)alloc(256); float* tr3 = (float*)alloc(256);
    float* tr4 = (float*)alloc(256); float* tr5 = (float*)alloc(256);
    float* tr6 = (float*)alloc(256); float* tr7 = (float*)alloc(256);

    const int B = 8192;

    pack_k<<<1, 256, 0, stream>>>(w1, w2, w3, w4, w5, wp1, wp2, wp3, wp4, wp5);

    // conv1: (B,1,1250) f32 -> (B,3,624p) ; P=8, R=3, grid 2731
    {
        int grid = (B + 2) / 3;
        conv_k<1, 3, 6, 1252, 623, 624, 8, 3, true, 1250>
            <<<grid, 256, 0, stream>>>(x, wp1, nullptr, y1, partial, B);
        finalize_k<<<3, 256, 0, stream>>>(partial, grid, 3, (double)B * 623.0, g[0], bb[0], tr2);
    }
    // conv2: (B,3,624p) -> (B,5,312p) ; P=4, R=4, grid 2048
    {
        int grid = B / 4;
        conv_k<3, 5, 5, 624, 310, 312, 4, 4, false>
            <<<grid, 256, 0, stream>>>(y1, wp2, tr2, y2, partial, B);
        finalize_k<<<5, 256, 0, stream>>>(partial, grid, 5, (double)B * 310.0, g[1], bb[1], tr3);
    }
    // conv3: (B,5,312p) -> (B,10,160p) ; P=2, R=4, grid 2048
    {
        int grid = B / 4;
        conv_k<5, 10, 4, 312, 154, 160, 2, 4, false>
            <<<grid, 256, 0, stream>>>(y2, wp3, tr3, y3, partial, B);
        finalize_k<<<10, 256, 0, stream>>>(partial, grid, 10, (double)B * 154.0, g[2], bb[2], tr4);
    }
    // conv4: (B,10,160p) -> (B,20,80p) ; P=1, R=4, grid 2048
    {
        int grid = B / 4;
        conv_k<10, 20, 4, 160, 76, 80, 1, 4, false>
            <<<grid, 256, 0, stream>>>(y3, wp4, tr4, y4, partial, B);
        finalize_k<<<20, 256, 0, stream>>>(partial, grid, 20, (double)B * 76.0, g[3], bb[3], tr5);
    }
    // conv5: (B,20,80p) -> (B,20,40p) ; P=1, R=8, grid 1024
    {
        int grid = B / 8;
        conv_k<20, 20, 4, 80, 37, 40, 1, 8, false>
            <<<grid, 256, 0, stream>>>(y4, wp5, tr5, y5, partial, B);
        finalize_k<<<20, 256, 0, stream>>>(partial, grid, 20, (double)B * 37.0, g[4], bb[4], tr6);
    }
    // fc1: (B,740) @ (10,740)^T ; grid 2048, one row-pass per wave
    {
        int grid = 2048;
        fc1_k<<<grid, 256, 0, stream>>>(y5, fw1, tr6, z1, partial, B);
        // fc2 + finalize(fc1) + stats + apply, fused single block
        fc2_fused_k<<<1, 256, 0, stream>>>(z1, fw2, partial, grid,
                                           g[5], bb[5], g[6], bb[6],
                                           (float*)d_out, B);
    }
}